// Round 3
// baseline (180.503 us; speedup 1.0000x reference)
//
#include <hip/hip_runtime.h>
#include <hip/hip_bf16.h>

// Encoding layer (Deep-TEN). B=16, D=128, K=32, N=H*W=4096.
// E[b,k,d] = sum_n A[b,n,k]*(X[b,n,d]-C[k,d]),  A = softmax_k(scale[k]*||X-C_k||^2)
// x layout: (B, D, H, W) -> X[b,n,d] = x[b*D*N + d*N + n]
//
// R3: kill pass1 latency chain. Each wave owns a 32-d quarter: 32 batched
// loads per thread (ONE wait point), partial xc[n][32k] in regs, ds_add_f32
// reduce into one shared plane (no 4x redundant loads). sC staged with
// quad-XOR swizzle (was 64-way bank conflict). 25.5KB LDS -> 4 blocks/CU,
// grid 1024 = exactly 4/CU, no tail.

#define D_    128
#define K_    32
#define NPB   64           // n per block
#define NTOT  4096         // H*W
#define SXLD  36           // sXC row stride (words): 32 xc + 1 x2 + pad

__global__ __launch_bounds__(256, 4) void enc_kernel(
    const float* __restrict__ x,
    const float* __restrict__ cw,
    const float* __restrict__ scale,
    float* __restrict__ out)
{
  __shared__ __align__(16) float sC[D_ * K_];    // C^T [d][quad-swizzled k], 16 KB
  __shared__ __align__(16) float sXC[NPB * SXLD]; // xc plane then A, 9.2 KB
  __shared__ float ssc[K_];
  __shared__ float sc2[K_];
  __shared__ float sasum[K_];

  const int t  = threadIdx.x;
  const int b  = blockIdx.x >> 6;
  const int n0 = (blockIdx.x & 63) * NPB;

  // ---- phase 0: zero accumulator plane + sc2 ----
  #pragma unroll
  for (int i = 0; i < 9; ++i) sXC[i * 256 + t] = 0.0f;
  if (t < K_) { sc2[t] = 0.0f; ssc[t] = scale[t]; }
  __syncthreads();

  // ---- stage C^T with quad swizzle; fuse c2 = ||C_k||^2 via LDS atomics ----
  #pragma unroll
  for (int i = 0; i < 16; ++i) {
    int idx = i * 256 + t;                       // 4096 = K*D, coalesced
    float v = cw[idx];
    int k = idx >> 7, d = idx & 127;
    int q = ((k >> 2) ^ (d & 7));                // physical quad (bank spread)
    sC[d * K_ + q * 4 + (k & 3)] = v;
    atomicAdd(&sc2[k], v * v);
  }

  // ---- pass 1 loads: wave owns d-quarter; issue ALL 32 upfront ----
  const int wq = t >> 6;                         // 0..3: d-quarter (wave-uniform)
  const int n  = t & 63;
  const float* xp = x + (size_t)b * D_ * NTOT + (size_t)wq * 32 * NTOT + n0 + n;
  float xv[32];
  #pragma unroll
  for (int i = 0; i < 32; ++i) xv[i] = xp[(size_t)i * NTOT];   // one batch, one wait
  __syncthreads();                               // sC ready

  // ---- pass 1 FMA: partial xc[n][all 32 k] over this wave's 32 d ----
  float acc[32];
  #pragma unroll
  for (int i = 0; i < 32; ++i) acc[i] = 0.0f;
  float x2 = 0.0f;
  const float4* sC4 = reinterpret_cast<const float4*>(sC);
  #pragma unroll
  for (int i = 0; i < 32; ++i) {
    float v = xv[i];                             // staggered vmcnt, in-order
    x2 = fmaf(v, v, x2);
    float4 c[8];
    // d = wq*32 + i; d&7 == i&7 (compile-time). logical quad lq = q ^ (i&7).
    #pragma unroll
    for (int q = 0; q < 8; ++q)
      c[q ^ (i & 7)] = sC4[(wq * 32 + i) * 8 + q];   // wave-uniform broadcast
    #pragma unroll
    for (int lq = 0; lq < 8; ++lq) {
      acc[4*lq+0] = fmaf(v, c[lq].x, acc[4*lq+0]);
      acc[4*lq+1] = fmaf(v, c[lq].y, acc[4*lq+1]);
      acc[4*lq+2] = fmaf(v, c[lq].z, acc[4*lq+2]);
      acc[4*lq+3] = fmaf(v, c[lq].w, acc[4*lq+3]);
    }
  }
  // reduce partials across the 4 waves into the shared plane
  #pragma unroll
  for (int k = 0; k < 32; ++k) atomicAdd(&sXC[n * SXLD + k], acc[k]);
  atomicAdd(&sXC[n * SXLD + 32], x2);
  __syncthreads();

  // ---- softmax over K=32: wave 0, thread t owns row n=t ----
  if (t < NPB) {
    float a[32];
    const float4* r4 = reinterpret_cast<const float4*>(&sXC[t * SXLD]);
    #pragma unroll
    for (int q = 0; q < 8; ++q) {
      float4 v = r4[q];
      a[4*q+0] = v.x; a[4*q+1] = v.y; a[4*q+2] = v.z; a[4*q+3] = v.w;
    }
    float xx2 = sXC[t * SXLD + 32];
    float m = -3.4e38f;
    #pragma unroll
    for (int k = 0; k < K_; ++k) {
      a[k] = ssc[k] * (xx2 - 2.0f * a[k] + sc2[k]);
      m = fmaxf(m, a[k]);
    }
    float s = 0.0f;
    #pragma unroll
    for (int k = 0; k < K_; ++k) { a[k] = __expf(a[k] - m); s += a[k]; }
    float inv = 1.0f / s;
    #pragma unroll
    for (int k = 0; k < K_; ++k) a[k] *= inv;
    // block asum[k] via single-wave butterfly; lane k keeps k's total
    float myasum = 0.0f;
    #pragma unroll
    for (int k = 0; k < K_; ++k) {
      float v = a[k];
      v += __shfl_xor(v, 1);
      v += __shfl_xor(v, 2);
      v += __shfl_xor(v, 4);
      v += __shfl_xor(v, 8);
      v += __shfl_xor(v, 16);
      v += __shfl_xor(v, 32);
      if (k == t) myasum = v;
    }
    if (t < K_) sasum[t] = myasum;
    float4* w4 = reinterpret_cast<float4*>(&sXC[t * SXLD]);  // overwrite row with A
    #pragma unroll
    for (int q = 0; q < 8; ++q)
      w4[q] = make_float4(a[4*q+0], a[4*q+1], a[4*q+2], a[4*q+3]);
  }
  __syncthreads();

  // ---- pass 2: E_p[k][d] = sum_n A[n,k]*X[n,d] - asum[k]*C[k,d] ----
  const int dd  = t & 63;
  const int kq2 = t >> 6;                        // wave-uniform
  const int k0  = kq2 * 8;
  const int d0  = dd * 2;
  float acc2[16];
  #pragma unroll
  for (int j = 0; j < 8; ++j) {                  // init = -asum*C, C from global (hot)
    float as = sasum[k0 + j];
    acc2[j]     = -as * cw[(k0 + j) * D_ + d0    ];
    acc2[8 + j] = -as * cw[(k0 + j) * D_ + d0 + 1];
  }
  const float* xq0 = x + (size_t)(b * D_ + d0) * NTOT + n0;
  const float* xq1 = xq0 + NTOT;
  #pragma unroll
  for (int half = 0; half < 2; ++half) {
    float4 xa[8], xb[8];
    #pragma unroll
    for (int j = 0; j < 8; ++j) {                // 16 b128 batched, then consume
      xa[j] = *reinterpret_cast<const float4*>(xq0 + half * 32 + 4 * j);
      xb[j] = *reinterpret_cast<const float4*>(xq1 + half * 32 + 4 * j);
    }
    #pragma unroll
    for (int j = 0; j < 8; ++j) {
      float xs0[4] = {xa[j].x, xa[j].y, xa[j].z, xa[j].w};
      float xs1[4] = {xb[j].x, xb[j].y, xb[j].z, xb[j].w};
      #pragma unroll
      for (int nn = 0; nn < 4; ++nn) {
        int row = half * 32 + 4 * j + nn;
        const float4* a4 = reinterpret_cast<const float4*>(&sXC[row * SXLD + k0]);
        float4 a0 = a4[0], a1 = a4[1];           // wave-uniform LDS broadcast
        float v0 = xs0[nn], v1 = xs1[nn];
        acc2[ 0] = fmaf(a0.x, v0, acc2[ 0]);
        acc2[ 1] = fmaf(a0.y, v0, acc2[ 1]);
        acc2[ 2] = fmaf(a0.z, v0, acc2[ 2]);
        acc2[ 3] = fmaf(a0.w, v0, acc2[ 3]);
        acc2[ 4] = fmaf(a1.x, v0, acc2[ 4]);
        acc2[ 5] = fmaf(a1.y, v0, acc2[ 5]);
        acc2[ 6] = fmaf(a1.z, v0, acc2[ 6]);
        acc2[ 7] = fmaf(a1.w, v0, acc2[ 7]);
        acc2[ 8] = fmaf(a0.x, v1, acc2[ 8]);
        acc2[ 9] = fmaf(a0.y, v1, acc2[ 9]);
        acc2[10] = fmaf(a0.z, v1, acc2[10]);
        acc2[11] = fmaf(a0.w, v1, acc2[11]);
        acc2[12] = fmaf(a1.x, v1, acc2[12]);
        acc2[13] = fmaf(a1.y, v1, acc2[13]);
        acc2[14] = fmaf(a1.z, v1, acc2[14]);
        acc2[15] = fmaf(a1.w, v1, acc2[15]);
      }
    }
  }
  float* op = out + (size_t)b * K_ * D_;
  #pragma unroll
  for (int j = 0; j < 8; ++j) {
    unsafeAtomicAdd(&op[(k0 + j) * D_ + d0    ], acc2[j]);
    unsafeAtomicAdd(&op[(k0 + j) * D_ + d0 + 1], acc2[8 + j]);
  }
}

extern "C" void kernel_launch(void* const* d_in, const int* in_sizes, int n_in,
                              void* d_out, int out_size, void* d_ws, size_t ws_size,
                              hipStream_t stream) {
  const float* x  = (const float*)d_in[0];
  const float* cw = (const float*)d_in[1];
  const float* sc = (const float*)d_in[2];
  float* out = (float*)d_out;
  const int B = in_sizes[0] / (D_ * NTOT);   // 16
  hipMemsetAsync(d_out, 0, (size_t)out_size * sizeof(float), stream);
  enc_kernel<<<dim3(B * (NTOT / NPB)), dim3(256), 0, stream>>>(x, cw, sc, out);
}

// Round 4
// 114.202 us; speedup vs baseline: 1.5806x; 1.5806x over previous
//
#include <hip/hip_runtime.h>
#include <hip/hip_bf16.h>

// Encoding layer (Deep-TEN). B=16, D=128, K=32, N=H*W=4096.
// E[b,k,d] = sum_n A[b,n,k]*(X[b,n,d]-C[k,d]),  A = softmax_k(scale[k]*||X-C_k||^2)
// x layout: (B, D, H, W) -> X[b,n,d] = x[b*D*N + d*N + n]
//
// R4: stage x tile in LDS once (coalesced, float4-XOR-swizzled) so BOTH passes
// read LDS: kills pass1's 4x-redundant global reads + 16 wait points AND
// pass2's 64-line gather. No register batch >8 (R3 spilled with xv[32]).
// C quad-swizzled (R3, proven). c2 without atomics. Softmax = R2 (proven).
// LDS 58.8KB -> 2 blocks/CU.

#define D_    128
#define K_    32
#define NPB   64           // n per block
#define NTOT  4096         // H*W
#define SP_LD 36           // sP row stride (words): 32 xc/A + x2 + pad

__global__ __launch_bounds__(256, 2) void enc_kernel(
    const float* __restrict__ x,
    const float* __restrict__ cw,
    const float* __restrict__ scale,
    float* __restrict__ out)
{
  __shared__ __align__(16) float sX[D_ * NPB];    // x tile, swizzled: 32 KB
  __shared__ __align__(16) float sC[D_ * K_];     // C^T quad-swizzled: 16 KB
  __shared__ __align__(16) float sP[NPB * SP_LD]; // xc -> A plane: 9.2 KB
  __shared__ float ssc[K_];
  __shared__ float sc2[K_];
  __shared__ float sasum[K_];

  const int t  = threadIdx.x;
  const int b  = blockIdx.x >> 6;
  const int n0 = (blockIdx.x & 63) * NPB;

  // ---- stage x tile (8 float4/thread, coalesced) + C (16 scalars/thread) ----
  const float* xb = x + (size_t)b * D_ * NTOT + n0;
  float4 xs[8];
  #pragma unroll
  for (int j = 0; j < 8; ++j) {
    int flat = j * 256 + t;                 // 2048 float4 = 128d x 16(n4)
    int d = flat >> 4, n4 = flat & 15;
    xs[j] = *reinterpret_cast<const float4*>(xb + (size_t)d * NTOT + n4 * 4);
  }
  float cv[16];
  #pragma unroll
  for (int i = 0; i < 16; ++i) cv[i] = cw[i * 256 + t];
  if (t < K_) ssc[t] = scale[t];
  #pragma unroll
  for (int j = 0; j < 8; ++j) {            // swizzled b128 LDS writes
    int flat = j * 256 + t;
    int d = flat >> 4, n4 = flat & 15;
    *reinterpret_cast<float4*>(&sX[d * NPB + ((n4 ^ ((d >> 1) & 15)) << 2)]) = xs[j];
  }
  #pragma unroll
  for (int i = 0; i < 16; ++i) {           // C^T [d][quad-swizzled k]
    int idx = i * 256 + t;
    int k = idx >> 7, d = idx & 127;
    int q = (k >> 2) ^ (d & 7);
    sC[d * K_ + q * 4 + (k & 3)] = cv[i];
  }
  __syncthreads();

  // ---- c2[k] = ||C_k||^2 (32 lanes, swizzle-aware, conflict-free) ----
  if (t < K_) {
    float s = 0.0f;
    #pragma unroll 8
    for (int d = 0; d < D_; ++d) {
      float c = sC[d * K_ + (((t >> 2) ^ (d & 7)) << 2) + (t & 3)];
      s = fmaf(c, c, s);
    }
    sc2[t] = s;
  }

  // ---- pass 1: xc[n][k0..k0+7] from LDS; x2 exact fp32 ----
  const int n  = t & 63;
  const int kq = t >> 6;                   // 0..3 (wave-uniform): 8-k group
  const int k0 = kq * 8;
  float acc[8];
  #pragma unroll
  for (int i = 0; i < 8; ++i) acc[i] = 0.0f;
  float x2 = 0.0f;
  const float4* sC4 = reinterpret_cast<const float4*>(sC);
  #pragma unroll 2
  for (int dc = 0; dc < D_; dc += 8) {
    float xv[8];
    #pragma unroll
    for (int i = 0; i < 8; ++i) {          // 8 LDS reads batched (2-way, free)
      int d = dc + i;
      xv[i] = sX[d * NPB + ((((n >> 2) ^ ((d >> 1) & 15)) << 2) | (n & 3))];
    }
    #pragma unroll
    for (int i = 0; i < 8; ++i) {
      int d = dc + i;
      float v = xv[i];
      x2 = fmaf(v, v, x2);
      float4 c0 = sC4[d * 8 + ((2 * kq) ^ (i & 7))];       // k0..k0+3
      float4 c1 = sC4[d * 8 + ((2 * kq + 1) ^ (i & 7))];   // k0+4..k0+7
      acc[0] = fmaf(v, c0.x, acc[0]);
      acc[1] = fmaf(v, c0.y, acc[1]);
      acc[2] = fmaf(v, c0.z, acc[2]);
      acc[3] = fmaf(v, c0.w, acc[3]);
      acc[4] = fmaf(v, c1.x, acc[4]);
      acc[5] = fmaf(v, c1.y, acc[5]);
      acc[6] = fmaf(v, c1.z, acc[6]);
      acc[7] = fmaf(v, c1.w, acc[7]);
    }
  }
  {
    float4* w4 = reinterpret_cast<float4*>(&sP[n * SP_LD + k0]);
    w4[0] = make_float4(acc[0], acc[1], acc[2], acc[3]);
    w4[1] = make_float4(acc[4], acc[5], acc[6], acc[7]);
    if (kq == 0) sP[n * SP_LD + 32] = x2;
  }
  __syncthreads();

  // ---- softmax over K=32: wave 0, thread t owns row n=t (R2, proven) ----
  if (t < NPB) {
    float a[32];
    const float4* r4 = reinterpret_cast<const float4*>(&sP[t * SP_LD]);
    #pragma unroll
    for (int q = 0; q < 8; ++q) {
      float4 v = r4[q];
      a[4*q+0] = v.x; a[4*q+1] = v.y; a[4*q+2] = v.z; a[4*q+3] = v.w;
    }
    float xx2 = sP[t * SP_LD + 32];
    float m = -3.4e38f;
    #pragma unroll
    for (int k = 0; k < K_; ++k) {
      a[k] = ssc[k] * (xx2 - 2.0f * a[k] + sc2[k]);
      m = fmaxf(m, a[k]);
    }
    float s = 0.0f;
    #pragma unroll
    for (int k = 0; k < K_; ++k) { a[k] = __expf(a[k] - m); s += a[k]; }
    float inv = 1.0f / s;
    #pragma unroll
    for (int k = 0; k < K_; ++k) a[k] *= inv;
    float myasum = 0.0f;
    #pragma unroll
    for (int k = 0; k < K_; ++k) {         // single-wave butterfly
      float v = a[k];
      v += __shfl_xor(v, 1);
      v += __shfl_xor(v, 2);
      v += __shfl_xor(v, 4);
      v += __shfl_xor(v, 8);
      v += __shfl_xor(v, 16);
      v += __shfl_xor(v, 32);
      if (k == t) myasum = v;
    }
    if (t < K_) sasum[t] = myasum;
    float4* w4 = reinterpret_cast<float4*>(&sP[t * SP_LD]);
    #pragma unroll
    for (int q = 0; q < 8; ++q)
      w4[q] = make_float4(a[4*q+0], a[4*q+1], a[4*q+2], a[4*q+3]);
  }
  __syncthreads();

  // ---- pass 2: E_p[k][d] = sum_n A[n,k]*X[n,d] - asum[k]*C[k,d], all-LDS ----
  const int dd  = t & 63;                  // d-pair owner
  const int kq2 = t >> 6;                  // wave-uniform
  const int k2  = kq2 * 8;
  const int drow = dd * 2 * NPB;           // sX row offset for d0=2*dd
  float acc2[16];
  #pragma unroll
  for (int j = 0; j < 8; ++j) {            // init = -asum*C (C from global, L2-hot)
    float as = sasum[k2 + j];
    acc2[j]     = -as * cw[(k2 + j) * D_ + dd * 2    ];
    acc2[8 + j] = -as * cw[(k2 + j) * D_ + dd * 2 + 1];
  }
  #pragma unroll 4
  for (int nb = 0; nb < NPB; nb += 4) {
    float xr0[4], xr1[4];
    float4 a0[4], a1[4];
    #pragma unroll
    for (int j = 0; j < 4; ++j) {          // batch 8 b32 + 8 bcast
      int nn = nb + j;
      int off = ((((nn >> 2) ^ (dd & 15)) << 2) | (nn & 3));
      xr0[j] = sX[drow + off];
      xr1[j] = sX[drow + NPB + off];
      const float4* a4 = reinterpret_cast<const float4*>(&sP[nn * SP_LD + k2]);
      a0[j] = a4[0]; a1[j] = a4[1];
    }
    #pragma unroll
    for (int j = 0; j < 4; ++j) {
      float v0 = xr0[j], v1 = xr1[j];
      acc2[ 0] = fmaf(a0[j].x, v0, acc2[ 0]);
      acc2[ 1] = fmaf(a0[j].y, v0, acc2[ 1]);
      acc2[ 2] = fmaf(a0[j].z, v0, acc2[ 2]);
      acc2[ 3] = fmaf(a0[j].w, v0, acc2[ 3]);
      acc2[ 4] = fmaf(a1[j].x, v0, acc2[ 4]);
      acc2[ 5] = fmaf(a1[j].y, v0, acc2[ 5]);
      acc2[ 6] = fmaf(a1[j].z, v0, acc2[ 6]);
      acc2[ 7] = fmaf(a1[j].w, v0, acc2[ 7]);
      acc2[ 8] = fmaf(a0[j].x, v1, acc2[ 8]);
      acc2[ 9] = fmaf(a0[j].y, v1, acc2[ 9]);
      acc2[10] = fmaf(a0[j].z, v1, acc2[10]);
      acc2[11] = fmaf(a0[j].w, v1, acc2[11]);
      acc2[12] = fmaf(a1[j].x, v1, acc2[12]);
      acc2[13] = fmaf(a1[j].y, v1, acc2[13]);
      acc2[14] = fmaf(a1[j].z, v1, acc2[14]);
      acc2[15] = fmaf(a1[j].w, v1, acc2[15]);
    }
  }
  float* op = out + (size_t)b * K_ * D_;
  #pragma unroll
  for (int j = 0; j < 8; ++j) {
    unsafeAtomicAdd(&op[(k2 + j) * D_ + dd * 2    ], acc2[j]);
    unsafeAtomicAdd(&op[(k2 + j) * D_ + dd * 2 + 1], acc2[8 + j]);
  }
}

extern "C" void kernel_launch(void* const* d_in, const int* in_sizes, int n_in,
                              void* d_out, int out_size, void* d_ws, size_t ws_size,
                              hipStream_t stream) {
  const float* x  = (const float*)d_in[0];
  const float* cw = (const float*)d_in[1];
  const float* sc = (const float*)d_in[2];
  float* out = (float*)d_out;
  const int B = in_sizes[0] / (D_ * NTOT);   // 16
  hipMemsetAsync(d_out, 0, (size_t)out_size * sizeof(float), stream);
  enc_kernel<<<dim3(B * (NTOT / NPB)), dim3(256), 0, stream>>>(x, cw, sc, out);
}

// Round 5
// 92.217 us; speedup vs baseline: 1.9574x; 1.2384x over previous
//
#include <hip/hip_runtime.h>
#include <hip/hip_bf16.h>

// Encoding layer (Deep-TEN). B=16, D=128, K=32, N=H*W=4096.
// E[b,k,d] = sum_n A[b,n,k]*(X[b,n,d]-C[k,d]),  A = softmax_k(scale[k]*||X-C_k||^2)
// x layout: (B, D, H, W) -> X[b,n,d] = x[d*NTOT + n]
//
// R5: bf16 MFMA for both contractions (threshold 6.08 >> bf16 error).
// pass1: xc = X*C^T via mfma_16x16x32_bf16, C^T frags resident in VGPRs
// (global, L1-hot), X from fp32 LDS tile [d][n] (XOR swizzle, exact x2).
// softmax in-register in ALL 4 waves (C/D layout, shfl reductions).
// pass2: E = A^T*X, A staged as 4KB bf16 LDS tile (b128 frags), -asum*C
// folded into acc init. LDS 36.5KB -> 4 blocks/CU.

#define D_   128
#define K_   32
#define NPB  64
#define NTOT 4096

typedef __attribute__((ext_vector_type(8))) short bf16x8;
typedef __attribute__((ext_vector_type(4))) float f32x4;

__device__ __forceinline__ short f2b(float f) {       // RNE fp32->bf16
  unsigned u = __float_as_uint(f);
  unsigned r = (u + 0x7FFFu + ((u >> 16) & 1u)) >> 16;
  return (short)r;
}

__global__ __launch_bounds__(256, 4) void enc_kernel(
    const float* __restrict__ x,
    const float* __restrict__ cw,
    const float* __restrict__ scale,
    float* __restrict__ out)
{
  __shared__ __align__(16) float sX[D_ * NPB];   // fp32 x-tile [d][n], swizzled, 32 KB
  __shared__ __align__(16) short sAb[K_ * NPB];  // bf16 A [k][n], swizzled, 4 KB
  __shared__ float sX2[NPB];
  __shared__ float sasum[K_];

  const int t  = threadIdx.x;
  const int w  = t >> 6;        // wave 0..3
  const int l  = t & 63;        // lane
  const int lr = l & 15;        // lane&15: row (A-ops) / col (B,C/D-ops)
  const int lg = l >> 4;        // lane group 0..3
  const int b  = blockIdx.x >> 6;
  const int n0 = (blockIdx.x & 63) * NPB;

  if (t < K_) sasum[t] = 0.0f;

  // ---- stage x tile: 8 dwordx4/thread, coalesced ----
  const float* xb = x + (size_t)b * D_ * NTOT + n0;
  float4 xs[8];
  #pragma unroll
  for (int j = 0; j < 8; ++j) {
    int flat = j * 256 + t;                 // 2048 float4 = 128d x 16(n4)
    int d = flat >> 4, n4 = flat & 15;
    xs[j] = *reinterpret_cast<const float4*>(xb + (size_t)d * NTOT + n4 * 4);
  }

  // ---- resident pass1 B-frags: C^T bf16 (global, L1-hot after 1st block) ----
  // lane holds C[k = lr+16*kt][d = 32*s + lg*8 + j]; c2 exact fp32 alongside
  bf16x8 bC[2][4];
  float c2p0 = 0.f, c2p1 = 0.f;
  #pragma unroll
  for (int kt = 0; kt < 2; ++kt) {
    const float* crow = cw + (lr + 16 * kt) * D_ + lg * 8;
    #pragma unroll
    for (int s = 0; s < 4; ++s) {
      float4 v0 = *reinterpret_cast<const float4*>(crow + 32 * s);
      float4 v1 = *reinterpret_cast<const float4*>(crow + 32 * s + 4);
      float vv[8] = {v0.x, v0.y, v0.z, v0.w, v1.x, v1.y, v1.z, v1.w};
      bf16x8 f;
      float cs = 0.f;
      #pragma unroll
      for (int j = 0; j < 8; ++j) { f[j] = f2b(vv[j]); cs = fmaf(vv[j], vv[j], cs); }
      bC[kt][s] = f;
      if (kt == 0) c2p0 += cs; else c2p1 += cs;
    }
  }
  c2p0 += __shfl_xor(c2p0, 16); c2p0 += __shfl_xor(c2p0, 32);  // full ||C_k||^2
  c2p1 += __shfl_xor(c2p1, 16); c2p1 += __shfl_xor(c2p1, 32);
  const float sc0 = scale[lr];
  const float sc1 = scale[lr + 16];

  // swizzled f4 writes: element (d,n) lives at float idx d*64 + (n ^ ((d&7)<<2))
  float4* sX4 = reinterpret_cast<float4*>(sX);
  #pragma unroll
  for (int j = 0; j < 8; ++j) {
    int flat = j * 256 + t;
    int d = flat >> 4, n4 = flat & 15;
    sX4[d * 16 + (n4 ^ (d & 7))] = xs[j];
  }
  __syncthreads();

  // ---- pass 1: xc tile [16n x 32k] per wave; exact x2 from fp32 frags ----
  const int m0 = w * 16;
  f32x4 p0 = {0.f, 0.f, 0.f, 0.f}, p1 = {0.f, 0.f, 0.f, 0.f};
  float x2p = 0.f;
  #pragma unroll
  for (int s = 0; s < 4; ++s) {
    int dbase = 32 * s + lg * 8;
    float av[8];
    #pragma unroll
    for (int j = 0; j < 8; ++j) {
      int d = dbase + j;
      av[j] = sX[d * 64 + ((m0 + lr) ^ ((d & 7) << 2))];
    }
    bf16x8 af;
    #pragma unroll
    for (int j = 0; j < 8; ++j) { af[j] = f2b(av[j]); x2p = fmaf(av[j], av[j], x2p); }
    p0 = __builtin_amdgcn_mfma_f32_16x16x32_bf16(af, bC[0][s], p0, 0, 0, 0);
    p1 = __builtin_amdgcn_mfma_f32_16x16x32_bf16(af, bC[1][s], p1, 0, 0, 0);
  }
  // x2 for row m0+lr (all lanes) -> bounce via LDS to C/D row owners
  x2p += __shfl_xor(x2p, 16);
  x2p += __shfl_xor(x2p, 32);
  if (lg == 0) sX2[m0 + lr] = x2p;     // per-wave disjoint rows; in-wave RAW
  float x2r[4];
  #pragma unroll
  for (int r = 0; r < 4; ++r) x2r[r] = sX2[m0 + lg * 4 + r];

  // ---- softmax over K=32, in-register (lane col k=lr(+16), rows lg*4+r) ----
  float a0[4], a1[4], mr[4], sr[4];
  #pragma unroll
  for (int r = 0; r < 4; ++r) {
    float sl0 = sc0 * (x2r[r] - 2.f * p0[r] + c2p0);
    float sl1 = sc1 * (x2r[r] - 2.f * p1[r] + c2p1);
    a0[r] = sl0; a1[r] = sl1;
    mr[r] = fmaxf(sl0, sl1);
  }
  #pragma unroll
  for (int dlt = 1; dlt <= 8; dlt <<= 1)
    #pragma unroll
    for (int r = 0; r < 4; ++r) mr[r] = fmaxf(mr[r], __shfl_xor(mr[r], dlt));
  #pragma unroll
  for (int r = 0; r < 4; ++r) {
    a0[r] = __expf(a0[r] - mr[r]);
    a1[r] = __expf(a1[r] - mr[r]);
    sr[r] = a0[r] + a1[r];
  }
  #pragma unroll
  for (int dlt = 1; dlt <= 8; dlt <<= 1)
    #pragma unroll
    for (int r = 0; r < 4; ++r) sr[r] += __shfl_xor(sr[r], dlt);
  #pragma unroll
  for (int r = 0; r < 4; ++r) {
    float inv = 1.0f / sr[r];
    a0[r] *= inv; a1[r] *= inv;
  }

  // ---- asum[k] (block) + A -> bf16 LDS tile [k][n] (16B-block XOR swz) ----
  float as0 = a0[0] + a0[1] + a0[2] + a0[3];
  float as1 = a1[0] + a1[1] + a1[2] + a1[3];
  as0 += __shfl_xor(as0, 16); as0 += __shfl_xor(as0, 32);
  as1 += __shfl_xor(as1, 16); as1 += __shfl_xor(as1, 32);
  if (lg == 0) {
    atomicAdd(&sasum[lr], as0);
    atomicAdd(&sasum[lr + 16], as1);
  }
  #pragma unroll
  for (int r = 0; r < 4; ++r) {
    int n = m0 + lg * 4 + r;
    int k0i = lr, k1i = lr + 16;
    sAb[k0i * 64 + (n ^ ((k0i & 7) << 3))] = f2b(a0[r]);
    sAb[k1i * 64 + (n ^ ((k1i & 7) << 3))] = f2b(a1[r]);
  }
  __syncthreads();

  // ---- pass 2: E[32k x 128d] = A^T X - asum*C; wave w owns d-tiles 2w,2w+1 ----
  bf16x8 aA[2][2];                      // A^T frags [mt][s]
  #pragma unroll
  for (int mt = 0; mt < 2; ++mt) {
    int k = mt * 16 + lr;
    #pragma unroll
    for (int s = 0; s < 2; ++s) {
      int nb = 32 * s + lg * 8;
      aA[mt][s] = *reinterpret_cast<const bf16x8*>(
          &sAb[k * 64 + (nb ^ ((k & 7) << 3))]);
    }
  }
  float asv[2][4];
  #pragma unroll
  for (int mt = 0; mt < 2; ++mt)
    #pragma unroll
    for (int r = 0; r < 4; ++r) asv[mt][r] = sasum[mt * 16 + lg * 4 + r];
  f32x4 acc[2][2];                      // [mt][dti]
  #pragma unroll
  for (int mt = 0; mt < 2; ++mt)
    #pragma unroll
    for (int dti = 0; dti < 2; ++dti) {
      int d = (2 * w + dti) * 16 + lr;
      #pragma unroll
      for (int r = 0; r < 4; ++r) {
        int k = mt * 16 + lg * 4 + r;
        acc[mt][dti][r] = -asv[mt][r] * cw[k * D_ + d];
      }
    }
  #pragma unroll
  for (int s = 0; s < 2; ++s) {
    #pragma unroll
    for (int dti = 0; dti < 2; ++dti) {
      int d = (2 * w + dti) * 16 + lr;
      int nb = 32 * s + lg * 8;
      int q0 = (nb >> 2) ^ (d & 7);         // logical f4-block -> physical
      int q1 = ((nb >> 2) + 1) ^ (d & 7);
      float4 v0 = sX4[d * 16 + q0];
      float4 v1 = sX4[d * 16 + q1];
      float vv[8] = {v0.x, v0.y, v0.z, v0.w, v1.x, v1.y, v1.z, v1.w};
      bf16x8 bf;
      #pragma unroll
      for (int j = 0; j < 8; ++j) bf[j] = f2b(vv[j]);
      acc[0][dti] = __builtin_amdgcn_mfma_f32_16x16x32_bf16(aA[0][s], bf, acc[0][dti], 0, 0, 0);
      acc[1][dti] = __builtin_amdgcn_mfma_f32_16x16x32_bf16(aA[1][s], bf, acc[1][dti], 0, 0, 0);
    }
  }
  float* op = out + (size_t)b * K_ * D_;
  #pragma unroll
  for (int mt = 0; mt < 2; ++mt)
    #pragma unroll
    for (int dti = 0; dti < 2; ++dti) {
      int d = (2 * w + dti) * 16 + lr;
      #pragma unroll
      for (int r = 0; r < 4; ++r) {
        int k = mt * 16 + lg * 4 + r;
        unsafeAtomicAdd(&op[k * D_ + d], acc[mt][dti][r]);
      }
    }
}

extern "C" void kernel_launch(void* const* d_in, const int* in_sizes, int n_in,
                              void* d_out, int out_size, void* d_ws, size_t ws_size,
                              hipStream_t stream) {
  const float* x  = (const float*)d_in[0];
  const float* cw = (const float*)d_in[1];
  const float* sc = (const float*)d_in[2];
  float* out = (float*)d_out;
  const int B = in_sizes[0] / (D_ * NTOT);   // 16
  hipMemsetAsync(d_out, 0, (size_t)out_size * sizeof(float), stream);
  enc_kernel<<<dim3(B * (NTOT / NPB)), dim3(256), 0, stream>>>(x, cw, sc, out);
}

// Round 6
// 91.126 us; speedup vs baseline: 1.9808x; 1.0120x over previous
//
#include <hip/hip_runtime.h>
#include <hip/hip_bf16.h>

// Encoding layer (Deep-TEN). B=16, D=128, K=32, N=H*W=4096.
// E[b,k,d] = sum_n A[b,n,k]*(X[b,n,d]-C[k,d]),  A = softmax_k(scale[k]*||X-C_k||^2)
// x layout: (B, D, H, W) -> X[b,n,d] = x[d*NTOT + n]
//
// R6: single-conversion bf16 LDS tiles. Staging thread owns 8-consecutive-d
// x 4-n block; converts once (__float2bfloat16 -> v_cvt_pk fusable), exact
// fp32 x2 via shfl, writes TWO swizzled bf16 tiles: [n][d] for pass1 A-frags
// and [d][n] for pass2 B-frags -> every MFMA fragment is ONE ds_read_b128,
// zero per-pass conversions. C-frags loaded after staging (latency hides
// under barrier). LDS 37.2KB -> 4 blocks/CU.

#define D_   128
#define K_   32
#define NPB  64
#define NTOT 4096

typedef __attribute__((ext_vector_type(8))) short bf16x8;
typedef __attribute__((ext_vector_type(4))) float f32x4;
typedef __attribute__((ext_vector_type(4))) short short4v;

__device__ __forceinline__ short f2b(float f) {   // RNE via HW cvt (compiler packs pairs)
  return (short)__builtin_bit_cast(unsigned short, __float2bfloat16(f));
}

__global__ __launch_bounds__(256, 4) void enc_kernel(
    const float* __restrict__ x,
    const float* __restrict__ cw,
    const float* __restrict__ scale,
    float* __restrict__ out)
{
  __shared__ __align__(16) short sNb[NPB * D_];  // bf16 X [n][d], blk-swizzled, 16 KB
  __shared__ __align__(16) short sDb[D_ * NPB];  // bf16 X [d][n], blk-swizzled, 16 KB
  __shared__ __align__(16) short sAb[K_ * NPB];  // bf16 A [k][n], blk-swizzled, 4 KB
  __shared__ __align__(16) float sX2w[NPB * 4];  // x2 partials [n][wave]
  __shared__ float sasum[K_];

  const int t  = threadIdx.x;
  const int w  = t >> 6;        // wave 0..3
  const int l  = t & 63;        // lane
  const int lr = l & 15;
  const int lg = l >> 4;
  const int b  = blockIdx.x >> 6;
  const int n0 = (blockIdx.x & 63) * NPB;

  if (t < K_) sasum[t] = 0.0f;

  // ---- staging: thread owns d = d0..d0+7 (consecutive), n = n4s*4..+3 ----
  const int n4s = t & 15;
  const int d0  = (t >> 4) * 8;          // = w*32 + lg*8
  const float* xb = x + (size_t)b * D_ * NTOT + n0;
  float4 xs[8];
  #pragma unroll
  for (int j = 0; j < 8; ++j)            // coalesced: 16 lanes span 256B per d
    xs[j] = *reinterpret_cast<const float4*>(xb + (size_t)(d0 + j) * NTOT + n4s * 4);

  // convert ONCE to bf16 (compiler CSE + cvt_pk)
  short xb16[8][4];
  #pragma unroll
  for (int j = 0; j < 8; ++j) {
    xb16[j][0] = f2b(xs[j].x); xb16[j][1] = f2b(xs[j].y);
    xb16[j][2] = f2b(xs[j].z); xb16[j][3] = f2b(xs[j].w);
  }
  // exact fp32 x2 partials over this thread's 8 d, then reduce over wave's 32 d
  float p2[4] = {0.f, 0.f, 0.f, 0.f};
  #pragma unroll
  for (int j = 0; j < 8; ++j) {
    p2[0] = fmaf(xs[j].x, xs[j].x, p2[0]);
    p2[1] = fmaf(xs[j].y, xs[j].y, p2[1]);
    p2[2] = fmaf(xs[j].z, xs[j].z, p2[2]);
    p2[3] = fmaf(xs[j].w, xs[j].w, p2[3]);
  }
  #pragma unroll
  for (int i = 0; i < 4; ++i) {
    p2[i] += __shfl_xor(p2[i], 16);
    p2[i] += __shfl_xor(p2[i], 32);
  }
  if (lg == 0) {                         // lanes 0..15: n4s == lr
    #pragma unroll
    for (int i = 0; i < 4; ++i) sX2w[(n4s * 4 + i) * 4 + w] = p2[i];
  }
  // sNb [n][d]: per n, 8 d-contiguous bf16 = one b128; phys16 = (d>>3)^(n&15)
  #pragma unroll
  for (int i = 0; i < 4; ++i) {
    int n = n4s * 4 + i;
    bf16x8 pk;
    #pragma unroll
    for (int j = 0; j < 8; ++j) pk[j] = xb16[j][i];
    int phys = ((d0 >> 3) ^ (n & 15)) & 15;
    *reinterpret_cast<bf16x8*>(&sNb[n * D_ + phys * 8]) = pk;
  }
  // sDb [d][n]: per d, 4 n-contiguous bf16 = one b64;
  // phys8 = (n>>3)^(d&7)^((d>>3)&7), in-block offset = n&7
  #pragma unroll
  for (int j = 0; j < 8; ++j) {
    int d = d0 + j;
    int phys = ((n4s >> 1) ^ (d & 7) ^ ((d >> 3) & 7)) & 7;
    short4v pk4 = {xb16[j][0], xb16[j][1], xb16[j][2], xb16[j][3]};
    *reinterpret_cast<short4v*>(&sDb[d * NPB + phys * 8 + (n4s & 1) * 4]) = pk4;
  }

  // ---- resident pass1 B-frags: C^T bf16 + exact c2 (latency hides under barrier)
  bf16x8 bC[2][4];
  float c2p0 = 0.f, c2p1 = 0.f;
  #pragma unroll
  for (int kt = 0; kt < 2; ++kt) {
    const float* crow = cw + (lr + 16 * kt) * D_ + lg * 8;
    #pragma unroll
    for (int s = 0; s < 4; ++s) {
      float4 v0 = *reinterpret_cast<const float4*>(crow + 32 * s);
      float4 v1 = *reinterpret_cast<const float4*>(crow + 32 * s + 4);
      float vv[8] = {v0.x, v0.y, v0.z, v0.w, v1.x, v1.y, v1.z, v1.w};
      bf16x8 f;
      float cs = 0.f;
      #pragma unroll
      for (int j = 0; j < 8; ++j) { f[j] = f2b(vv[j]); cs = fmaf(vv[j], vv[j], cs); }
      bC[kt][s] = f;
      if (kt == 0) c2p0 += cs; else c2p1 += cs;
    }
  }
  c2p0 += __shfl_xor(c2p0, 16); c2p0 += __shfl_xor(c2p0, 32);
  c2p1 += __shfl_xor(c2p1, 16); c2p1 += __shfl_xor(c2p1, 32);
  const float sc0 = scale[lr];
  const float sc1 = scale[lr + 16];
  __syncthreads();

  // ---- pass 1: xc tile [16n x 32k] per wave; A-frag = 1 ds_read_b128 ----
  const int m0 = w * 16;
  const int nrow = m0 + lr;
  f32x4 p0 = {0.f, 0.f, 0.f, 0.f}, p1 = {0.f, 0.f, 0.f, 0.f};
  #pragma unroll
  for (int s = 0; s < 4; ++s) {
    int dblk = 4 * s + lg;
    bf16x8 af = *reinterpret_cast<const bf16x8*>(
        &sNb[nrow * D_ + ((dblk ^ lr) & 15) * 8]);
    p0 = __builtin_amdgcn_mfma_f32_16x16x32_bf16(af, bC[0][s], p0, 0, 0, 0);
    p1 = __builtin_amdgcn_mfma_f32_16x16x32_bf16(af, bC[1][s], p1, 0, 0, 0);
  }
  float x2r[4];
  #pragma unroll
  for (int r = 0; r < 4; ++r) {
    float4 v = *reinterpret_cast<const float4*>(&sX2w[(m0 + lg * 4 + r) * 4]);
    x2r[r] = (v.x + v.y) + (v.z + v.w);
  }

  // ---- softmax over K=32, in-register (lane col k=lr(+16), rows lg*4+r) ----
  float a0[4], a1[4], mr[4], sr[4];
  #pragma unroll
  for (int r = 0; r < 4; ++r) {
    float sl0 = sc0 * (x2r[r] - 2.f * p0[r] + c2p0);
    float sl1 = sc1 * (x2r[r] - 2.f * p1[r] + c2p1);
    a0[r] = sl0; a1[r] = sl1;
    mr[r] = fmaxf(sl0, sl1);
  }
  #pragma unroll
  for (int dlt = 1; dlt <= 8; dlt <<= 1)
    #pragma unroll
    for (int r = 0; r < 4; ++r) mr[r] = fmaxf(mr[r], __shfl_xor(mr[r], dlt));
  #pragma unroll
  for (int r = 0; r < 4; ++r) {
    a0[r] = __expf(a0[r] - mr[r]);
    a1[r] = __expf(a1[r] - mr[r]);
    sr[r] = a0[r] + a1[r];
  }
  #pragma unroll
  for (int dlt = 1; dlt <= 8; dlt <<= 1)
    #pragma unroll
    for (int r = 0; r < 4; ++r) sr[r] += __shfl_xor(sr[r], dlt);
  #pragma unroll
  for (int r = 0; r < 4; ++r) {
    float inv = 1.0f / sr[r];
    a0[r] *= inv; a1[r] *= inv;
  }

  // ---- asum[k] (block) + A -> bf16 LDS tile [k][n] ----
  float as0 = a0[0] + a0[1] + a0[2] + a0[3];
  float as1 = a1[0] + a1[1] + a1[2] + a1[3];
  as0 += __shfl_xor(as0, 16); as0 += __shfl_xor(as0, 32);
  as1 += __shfl_xor(as1, 16); as1 += __shfl_xor(as1, 32);
  if (lg == 0) {
    atomicAdd(&sasum[lr], as0);
    atomicAdd(&sasum[lr + 16], as1);
  }
  #pragma unroll
  for (int r = 0; r < 4; ++r) {
    int n = m0 + lg * 4 + r;
    sAb[lr * 64 + (n ^ ((lr & 7) << 3))] = f2b(a0[r]);
    sAb[(lr + 16) * 64 + (n ^ (((lr + 16) & 7) << 3))] = f2b(a1[r]);
  }
  __syncthreads();

  // ---- pass 2: E[32k x 128d] = A^T X - asum*C; wave w owns d-tiles 2w,2w+1 ----
  bf16x8 aA[2][2];
  #pragma unroll
  for (int mt = 0; mt < 2; ++mt) {
    int k = mt * 16 + lr;
    #pragma unroll
    for (int s = 0; s < 2; ++s) {
      int nb = 32 * s + lg * 8;
      aA[mt][s] = *reinterpret_cast<const bf16x8*>(
          &sAb[k * 64 + (nb ^ ((k & 7) << 3))]);
    }
  }
  float asv[2][4];
  #pragma unroll
  for (int mt = 0; mt < 2; ++mt)
    #pragma unroll
    for (int r = 0; r < 4; ++r) asv[mt][r] = sasum[mt * 16 + lg * 4 + r];
  f32x4 acc[2][2];
  #pragma unroll
  for (int mt = 0; mt < 2; ++mt)
    #pragma unroll
    for (int dti = 0; dti < 2; ++dti) {
      int d = (2 * w + dti) * 16 + lr;
      #pragma unroll
      for (int r = 0; r < 4; ++r) {
        int k = mt * 16 + lg * 4 + r;
        acc[mt][dti][r] = -asv[mt][r] * cw[k * D_ + d];
      }
    }
  #pragma unroll
  for (int s = 0; s < 2; ++s) {
    #pragma unroll
    for (int dti = 0; dti < 2; ++dti) {
      int d = (2 * w + dti) * 16 + lr;
      int phys = (((4 * s + lg) ^ (d & 7) ^ ((d >> 3) & 7)) & 7);
      bf16x8 bf = *reinterpret_cast<const bf16x8*>(&sDb[d * NPB + phys * 8]);
      acc[0][dti] = __builtin_amdgcn_mfma_f32_16x16x32_bf16(aA[0][s], bf, acc[0][dti], 0, 0, 0);
      acc[1][dti] = __builtin_amdgcn_mfma_f32_16x16x32_bf16(aA[1][s], bf, acc[1][dti], 0, 0, 0);
    }
  }
  float* op = out + (size_t)b * K_ * D_;
  #pragma unroll
  for (int mt = 0; mt < 2; ++mt)
    #pragma unroll
    for (int dti = 0; dti < 2; ++dti) {
      int d = (2 * w + dti) * 16 + lr;
      #pragma unroll
      for (int r = 0; r < 4; ++r) {
        int k = mt * 16 + lg * 4 + r;
        unsafeAtomicAdd(&op[k * D_ + d], acc[mt][dti][r]);
      }
    }
}

extern "C" void kernel_launch(void* const* d_in, const int* in_sizes, int n_in,
                              void* d_out, int out_size, void* d_ws, size_t ws_size,
                              hipStream_t stream) {
  const float* x  = (const float*)d_in[0];
  const float* cw = (const float*)d_in[1];
  const float* sc = (const float*)d_in[2];
  float* out = (float*)d_out;
  const int B = in_sizes[0] / (D_ * NTOT);   // 16
  hipMemsetAsync(d_out, 0, (size_t)out_size * sizeof(float), stream);
  enc_kernel<<<dim3(B * (NTOT / NPB)), dim3(256), 0, stream>>>(x, cw, sc, out);
}

// Round 7
// 89.769 us; speedup vs baseline: 2.0107x; 1.0151x over previous
//
#include <hip/hip_runtime.h>
#include <hip/hip_bf16.h>

// Encoding layer (Deep-TEN). B=16, D=128, K=32, N=H*W=4096.
// E[b,k,d] = sum_n A[b,n,k]*(X[b,n,d]-C[k,d]),  A = softmax_k(scale[k]*||X-C_k||^2)
// x layout: (B, D, H, W) -> X[b,n,d] = x[d*NTOT + n]
//
// R7: pipeline 2 n-tiles per block (grid 512). Tile1 global loads issued
// before tile0 compute (reg-staged, latency hides under MFMA+softmax).
// Pass2 accumulator + asum persist in regs across tiles; single -asum*C
// correction and ONE atomic flush at the end (atomic traffic halved).
// Swizzled bf16 tiles from R6 (proven): sNb [n][d] pass1 A-frags,
// sDb [d][n] pass2 B-frags, sAb [k][n]; every frag = 1 ds_read_b128.

#define D_   128
#define K_   32
#define NPB  64
#define NTOT 4096

typedef __attribute__((ext_vector_type(8))) short bf16x8;
typedef __attribute__((ext_vector_type(4))) float f32x4;
typedef __attribute__((ext_vector_type(4))) short short4v;

__device__ __forceinline__ short f2b(float f) {
  return (short)__builtin_bit_cast(unsigned short, __float2bfloat16(f));
}

__global__ __launch_bounds__(256, 2) void enc_kernel(
    const float* __restrict__ x,
    const float* __restrict__ cw,
    const float* __restrict__ scale,
    float* __restrict__ out)
{
  __shared__ __align__(16) short sNb[NPB * D_];  // bf16 X [n][d] swz, 16 KB
  __shared__ __align__(16) short sDb[D_ * NPB];  // bf16 X [d][n] swz, 16 KB
  __shared__ __align__(16) short sAb[K_ * NPB];  // bf16 A [k][n] swz, 4 KB
  __shared__ __align__(16) float sX2w[NPB * 4];
  __shared__ float sasum[K_];

  const int t  = threadIdx.x;
  const int w  = t >> 6;
  const int l  = t & 63;
  const int lr = l & 15;
  const int lg = l >> 4;
  const int b  = blockIdx.x >> 5;               // 32 blocks per b
  const int nbase = (blockIdx.x & 31) * 128;    // 2 tiles of 64

  const int n4s = t & 15;
  const int d0  = (t >> 4) * 8;
  const float* xb = x + (size_t)b * D_ * NTOT + nbase;

  // ---- resident pass1 B-frags: C^T bf16 + exact c2 (issued first, tiny) ----
  bf16x8 bC[2][4];
  float c2p0 = 0.f, c2p1 = 0.f;
  #pragma unroll
  for (int kt = 0; kt < 2; ++kt) {
    const float* crow = cw + (lr + 16 * kt) * D_ + lg * 8;
    #pragma unroll
    for (int s = 0; s < 4; ++s) {
      float4 v0 = *reinterpret_cast<const float4*>(crow + 32 * s);
      float4 v1 = *reinterpret_cast<const float4*>(crow + 32 * s + 4);
      float vv[8] = {v0.x, v0.y, v0.z, v0.w, v1.x, v1.y, v1.z, v1.w};
      bf16x8 f;
      float cs = 0.f;
      #pragma unroll
      for (int j = 0; j < 8; ++j) { f[j] = f2b(vv[j]); cs = fmaf(vv[j], vv[j], cs); }
      bC[kt][s] = f;
      if (kt == 0) c2p0 += cs; else c2p1 += cs;
    }
  }
  c2p0 += __shfl_xor(c2p0, 16); c2p0 += __shfl_xor(c2p0, 32);
  c2p1 += __shfl_xor(c2p1, 16); c2p1 += __shfl_xor(c2p1, 32);
  const float sc0 = scale[lr];
  const float sc1 = scale[lr + 16];

  // ---- prologue: load + stage tile 0 ----
  float4 xs[8];
  #pragma unroll
  for (int j = 0; j < 8; ++j)
    xs[j] = *reinterpret_cast<const float4*>(xb + (size_t)(d0 + j) * NTOT + n4s * 4);
  if (t < K_) sasum[t] = 0.0f;

  #define STAGE_TILE()                                                        \
  {                                                                           \
    short xb16[8][4];                                                         \
    _Pragma("unroll")                                                         \
    for (int j = 0; j < 8; ++j) {                                             \
      xb16[j][0] = f2b(xs[j].x); xb16[j][1] = f2b(xs[j].y);                   \
      xb16[j][2] = f2b(xs[j].z); xb16[j][3] = f2b(xs[j].w);                   \
    }                                                                         \
    float p2[4] = {0.f, 0.f, 0.f, 0.f};                                       \
    _Pragma("unroll")                                                         \
    for (int j = 0; j < 8; ++j) {                                             \
      p2[0] = fmaf(xs[j].x, xs[j].x, p2[0]);                                  \
      p2[1] = fmaf(xs[j].y, xs[j].y, p2[1]);                                  \
      p2[2] = fmaf(xs[j].z, xs[j].z, p2[2]);                                  \
      p2[3] = fmaf(xs[j].w, xs[j].w, p2[3]);                                  \
    }                                                                         \
    _Pragma("unroll")                                                         \
    for (int i = 0; i < 4; ++i) {                                             \
      p2[i] += __shfl_xor(p2[i], 16);                                         \
      p2[i] += __shfl_xor(p2[i], 32);                                         \
    }                                                                         \
    if (lg == 0) {                                                            \
      _Pragma("unroll")                                                       \
      for (int i = 0; i < 4; ++i) sX2w[(n4s * 4 + i) * 4 + w] = p2[i];        \
    }                                                                         \
    _Pragma("unroll")                                                         \
    for (int i = 0; i < 4; ++i) {                                             \
      int n = n4s * 4 + i;                                                    \
      bf16x8 pk;                                                              \
      _Pragma("unroll")                                                       \
      for (int j = 0; j < 8; ++j) pk[j] = xb16[j][i];                         \
      int phys = ((d0 >> 3) ^ (n & 15)) & 15;                                 \
      *reinterpret_cast<bf16x8*>(&sNb[n * D_ + phys * 8]) = pk;               \
    }                                                                         \
    _Pragma("unroll")                                                         \
    for (int j = 0; j < 8; ++j) {                                             \
      int d = d0 + j;                                                         \
      int phys = ((n4s >> 1) ^ (d & 7) ^ ((d >> 3) & 7)) & 7;                 \
      short4v pk4 = {xb16[j][0], xb16[j][1], xb16[j][2], xb16[j][3]};         \
      *reinterpret_cast<short4v*>(&sDb[d * NPB + phys * 8 + (n4s & 1) * 4]) = pk4; \
    }                                                                         \
  }

  STAGE_TILE();
  __syncthreads();

  const int m0 = w * 16;
  const int nrow = m0 + lr;
  f32x4 acc[2][2];
  float asvT[2][4];
  #pragma unroll
  for (int mt = 0; mt < 2; ++mt) {
    #pragma unroll
    for (int dti = 0; dti < 2; ++dti) acc[mt][dti] = (f32x4){0.f, 0.f, 0.f, 0.f};
    #pragma unroll
    for (int r = 0; r < 4; ++r) asvT[mt][r] = 0.f;
  }

  #pragma unroll
  for (int tile = 0; tile < 2; ++tile) {
    if (tile == 0) {                     // prefetch tile1: in flight under compute
      #pragma unroll
      for (int j = 0; j < 8; ++j)
        xs[j] = *reinterpret_cast<const float4*>(
            xb + 64 + (size_t)(d0 + j) * NTOT + n4s * 4);
    }

    // ---- pass 1: xc tile [16n x 32k] per wave ----
    f32x4 p0 = {0.f, 0.f, 0.f, 0.f}, p1 = {0.f, 0.f, 0.f, 0.f};
    #pragma unroll
    for (int s = 0; s < 4; ++s) {
      int dblk = 4 * s + lg;
      bf16x8 af = *reinterpret_cast<const bf16x8*>(
          &sNb[nrow * D_ + ((dblk ^ lr) & 15) * 8]);
      p0 = __builtin_amdgcn_mfma_f32_16x16x32_bf16(af, bC[0][s], p0, 0, 0, 0);
      p1 = __builtin_amdgcn_mfma_f32_16x16x32_bf16(af, bC[1][s], p1, 0, 0, 0);
    }
    float x2r[4];
    #pragma unroll
    for (int r = 0; r < 4; ++r) {
      float4 v = *reinterpret_cast<const float4*>(&sX2w[(m0 + lg * 4 + r) * 4]);
      x2r[r] = (v.x + v.y) + (v.z + v.w);
    }

    // ---- softmax over K=32 in-register ----
    float a0[4], a1[4], mr[4], sr[4];
    #pragma unroll
    for (int r = 0; r < 4; ++r) {
      float sl0 = sc0 * (x2r[r] - 2.f * p0[r] + c2p0);
      float sl1 = sc1 * (x2r[r] - 2.f * p1[r] + c2p1);
      a0[r] = sl0; a1[r] = sl1;
      mr[r] = fmaxf(sl0, sl1);
    }
    #pragma unroll
    for (int dlt = 1; dlt <= 8; dlt <<= 1)
      #pragma unroll
      for (int r = 0; r < 4; ++r) mr[r] = fmaxf(mr[r], __shfl_xor(mr[r], dlt));
    #pragma unroll
    for (int r = 0; r < 4; ++r) {
      a0[r] = __expf(a0[r] - mr[r]);
      a1[r] = __expf(a1[r] - mr[r]);
      sr[r] = a0[r] + a1[r];
    }
    #pragma unroll
    for (int dlt = 1; dlt <= 8; dlt <<= 1)
      #pragma unroll
      for (int r = 0; r < 4; ++r) sr[r] += __shfl_xor(sr[r], dlt);
    #pragma unroll
    for (int r = 0; r < 4; ++r) {
      float inv = 1.0f / sr[r];
      a0[r] *= inv; a1[r] *= inv;
    }

    // ---- block asum + A -> bf16 LDS tile ----
    float as0 = a0[0] + a0[1] + a0[2] + a0[3];
    float as1 = a1[0] + a1[1] + a1[2] + a1[3];
    as0 += __shfl_xor(as0, 16); as0 += __shfl_xor(as0, 32);
    as1 += __shfl_xor(as1, 16); as1 += __shfl_xor(as1, 32);
    if (lg == 0) {
      atomicAdd(&sasum[lr], as0);
      atomicAdd(&sasum[lr + 16], as1);
    }
    #pragma unroll
    for (int r = 0; r < 4; ++r) {
      int n = m0 + lg * 4 + r;
      sAb[lr * 64 + (n ^ ((lr & 7) << 3))] = f2b(a0[r]);
      sAb[(lr + 16) * 64 + (n ^ (((lr + 16) & 7) << 3))] = f2b(a1[r]);
    }
    __syncthreads();

    // ---- pass 2 accumulate: E += A^T X ----
    bf16x8 aA[2][2];
    #pragma unroll
    for (int mt = 0; mt < 2; ++mt) {
      int k = mt * 16 + lr;
      #pragma unroll
      for (int s = 0; s < 2; ++s) {
        int nb = 32 * s + lg * 8;
        aA[mt][s] = *reinterpret_cast<const bf16x8*>(
            &sAb[k * 64 + (nb ^ ((k & 7) << 3))]);
      }
    }
    #pragma unroll
    for (int mt = 0; mt < 2; ++mt)
      #pragma unroll
      for (int r = 0; r < 4; ++r) asvT[mt][r] += sasum[mt * 16 + lg * 4 + r];
    #pragma unroll
    for (int s = 0; s < 2; ++s) {
      #pragma unroll
      for (int dti = 0; dti < 2; ++dti) {
        int d = (2 * w + dti) * 16 + lr;
        int phys = (((4 * s + lg) ^ (d & 7) ^ ((d >> 3) & 7)) & 7);
        bf16x8 bf = *reinterpret_cast<const bf16x8*>(&sDb[d * NPB + phys * 8]);
        acc[0][dti] = __builtin_amdgcn_mfma_f32_16x16x32_bf16(aA[0][s], bf, acc[0][dti], 0, 0, 0);
        acc[1][dti] = __builtin_amdgcn_mfma_f32_16x16x32_bf16(aA[1][s], bf, acc[1][dti], 0, 0, 0);
      }
    }
    __syncthreads();                      // sNb/sDb/sAb/sX2w free for next tile

    if (tile == 0) {
      if (t < K_) sasum[t] = 0.0f;        // re-zero (barrier below orders vs atomics)
      STAGE_TILE();
      __syncthreads();
    }
  }

  // ---- epilogue: -asum*C correction + single atomic flush ----
  float* op = out + (size_t)b * K_ * D_;
  #pragma unroll
  for (int mt = 0; mt < 2; ++mt)
    #pragma unroll
    for (int dti = 0; dti < 2; ++dti) {
      int d = (2 * w + dti) * 16 + lr;
      #pragma unroll
      for (int r = 0; r < 4; ++r) {
        int k = mt * 16 + lg * 4 + r;
        float v = acc[mt][dti][r] - asvT[mt][r] * cw[k * D_ + d];
        unsafeAtomicAdd(&op[k * D_ + d], v);
      }
    }
}

extern "C" void kernel_launch(void* const* d_in, const int* in_sizes, int n_in,
                              void* d_out, int out_size, void* d_ws, size_t ws_size,
                              hipStream_t stream) {
  const float* x  = (const float*)d_in[0];
  const float* cw = (const float*)d_in[1];
  const float* sc = (const float*)d_in[2];
  float* out = (float*)d_out;
  const int B = in_sizes[0] / (D_ * NTOT);   // 16
  hipMemsetAsync(d_out, 0, (size_t)out_size * sizeof(float), stream);
  enc_kernel<<<dim3(B * 32), dim3(256), 0, stream>>>(x, cw, sc, out);
}

// Round 8
// 85.072 us; speedup vs baseline: 2.1218x; 1.0552x over previous
//
#include <hip/hip_runtime.h>
#include <hip/hip_bf16.h>

// Encoding layer (Deep-TEN). B=16, D=128, K=32, N=H*W=4096.
// E[b,k,d] = sum_n A[b,n,k]*(X[b,n,d]-C[k,d]),  A = softmax_k(scale[k]*||X-C_k||^2)
// x layout: (B, D, H, W) -> X[b,n,d] = x[d*NTOT + n]
//
// R8: kill the global-atomic tail (R2/R4 counters: 33MB HBM write-through for
// a 256KB output; ~2M fp32 r-m-w serializing per cacheline ~= the stuck 25us).
// k1 = R7 pipeline, but each block stores its 16KB partial E to d_ws with
// plain coalesced stores (8MB streaming, no contention, no memset dep).
// k2 = reduce: 16K threads sum 32 float4 partials -> out. No atomics anywhere.

#define D_   128
#define K_   32
#define NPB  64
#define NTOT 4096

typedef __attribute__((ext_vector_type(8))) short bf16x8;
typedef __attribute__((ext_vector_type(4))) float f32x4;
typedef __attribute__((ext_vector_type(4))) short short4v;

__device__ __forceinline__ short f2b(float f) {
  return (short)__builtin_bit_cast(unsigned short, __float2bfloat16(f));
}

__global__ __launch_bounds__(256, 2) void enc_kernel(
    const float* __restrict__ x,
    const float* __restrict__ cw,
    const float* __restrict__ scale,
    float* __restrict__ ws)
{
  __shared__ __align__(16) short sNb[NPB * D_];  // bf16 X [n][d] swz, 16 KB
  __shared__ __align__(16) short sDb[D_ * NPB];  // bf16 X [d][n] swz, 16 KB
  __shared__ __align__(16) short sAb[K_ * NPB];  // bf16 A [k][n] swz, 4 KB
  __shared__ __align__(16) float sX2w[NPB * 4];
  __shared__ float sasum[K_];

  const int t  = threadIdx.x;
  const int w  = t >> 6;
  const int l  = t & 63;
  const int lr = l & 15;
  const int lg = l >> 4;
  const int b  = blockIdx.x >> 5;               // 32 blocks per b
  const int nbase = (blockIdx.x & 31) * 128;    // 2 tiles of 64

  const int n4s = t & 15;
  const int d0  = (t >> 4) * 8;
  const float* xb = x + (size_t)b * D_ * NTOT + nbase;

  // ---- resident pass1 B-frags: C^T bf16 + exact c2 ----
  bf16x8 bC[2][4];
  float c2p0 = 0.f, c2p1 = 0.f;
  #pragma unroll
  for (int kt = 0; kt < 2; ++kt) {
    const float* crow = cw + (lr + 16 * kt) * D_ + lg * 8;
    #pragma unroll
    for (int s = 0; s < 4; ++s) {
      float4 v0 = *reinterpret_cast<const float4*>(crow + 32 * s);
      float4 v1 = *reinterpret_cast<const float4*>(crow + 32 * s + 4);
      float vv[8] = {v0.x, v0.y, v0.z, v0.w, v1.x, v1.y, v1.z, v1.w};
      bf16x8 f;
      float cs = 0.f;
      #pragma unroll
      for (int j = 0; j < 8; ++j) { f[j] = f2b(vv[j]); cs = fmaf(vv[j], vv[j], cs); }
      bC[kt][s] = f;
      if (kt == 0) c2p0 += cs; else c2p1 += cs;
    }
  }
  c2p0 += __shfl_xor(c2p0, 16); c2p0 += __shfl_xor(c2p0, 32);
  c2p1 += __shfl_xor(c2p1, 16); c2p1 += __shfl_xor(c2p1, 32);
  const float sc0 = scale[lr];
  const float sc1 = scale[lr + 16];

  // ---- prologue: load + stage tile 0 ----
  float4 xs[8];
  #pragma unroll
  for (int j = 0; j < 8; ++j)
    xs[j] = *reinterpret_cast<const float4*>(xb + (size_t)(d0 + j) * NTOT + n4s * 4);
  if (t < K_) sasum[t] = 0.0f;

  #define STAGE_TILE()                                                        \
  {                                                                           \
    short xb16[8][4];                                                         \
    _Pragma("unroll")                                                         \
    for (int j = 0; j < 8; ++j) {                                             \
      xb16[j][0] = f2b(xs[j].x); xb16[j][1] = f2b(xs[j].y);                   \
      xb16[j][2] = f2b(xs[j].z); xb16[j][3] = f2b(xs[j].w);                   \
    }                                                                         \
    float p2[4] = {0.f, 0.f, 0.f, 0.f};                                       \
    _Pragma("unroll")                                                         \
    for (int j = 0; j < 8; ++j) {                                             \
      p2[0] = fmaf(xs[j].x, xs[j].x, p2[0]);                                  \
      p2[1] = fmaf(xs[j].y, xs[j].y, p2[1]);                                  \
      p2[2] = fmaf(xs[j].z, xs[j].z, p2[2]);                                  \
      p2[3] = fmaf(xs[j].w, xs[j].w, p2[3]);                                  \
    }                                                                         \
    _Pragma("unroll")                                                         \
    for (int i = 0; i < 4; ++i) {                                             \
      p2[i] += __shfl_xor(p2[i], 16);                                         \
      p2[i] += __shfl_xor(p2[i], 32);                                         \
    }                                                                         \
    if (lg == 0) {                                                            \
      _Pragma("unroll")                                                       \
      for (int i = 0; i < 4; ++i) sX2w[(n4s * 4 + i) * 4 + w] = p2[i];        \
    }                                                                         \
    _Pragma("unroll")                                                         \
    for (int i = 0; i < 4; ++i) {                                             \
      int n = n4s * 4 + i;                                                    \
      bf16x8 pk;                                                              \
      _Pragma("unroll")                                                       \
      for (int j = 0; j < 8; ++j) pk[j] = xb16[j][i];                         \
      int phys = ((d0 >> 3) ^ (n & 15)) & 15;                                 \
      *reinterpret_cast<bf16x8*>(&sNb[n * D_ + phys * 8]) = pk;               \
    }                                                                         \
    _Pragma("unroll")                                                         \
    for (int j = 0; j < 8; ++j) {                                             \
      int d = d0 + j;                                                         \
      int phys = ((n4s >> 1) ^ (d & 7) ^ ((d >> 3) & 7)) & 7;                 \
      short4v pk4 = {xb16[j][0], xb16[j][1], xb16[j][2], xb16[j][3]};         \
      *reinterpret_cast<short4v*>(&sDb[d * NPB + phys * 8 + (n4s & 1) * 4]) = pk4; \
    }                                                                         \
  }

  STAGE_TILE();
  __syncthreads();

  const int m0 = w * 16;
  const int nrow = m0 + lr;
  f32x4 acc[2][2];
  float asvT[2][4];
  #pragma unroll
  for (int mt = 0; mt < 2; ++mt) {
    #pragma unroll
    for (int dti = 0; dti < 2; ++dti) acc[mt][dti] = (f32x4){0.f, 0.f, 0.f, 0.f};
    #pragma unroll
    for (int r = 0; r < 4; ++r) asvT[mt][r] = 0.f;
  }

  #pragma unroll
  for (int tile = 0; tile < 2; ++tile) {
    if (tile == 0) {                     // prefetch tile1: in flight under compute
      #pragma unroll
      for (int j = 0; j < 8; ++j)
        xs[j] = *reinterpret_cast<const float4*>(
            xb + 64 + (size_t)(d0 + j) * NTOT + n4s * 4);
    }

    // ---- pass 1: xc tile [16n x 32k] per wave ----
    f32x4 p0 = {0.f, 0.f, 0.f, 0.f}, p1 = {0.f, 0.f, 0.f, 0.f};
    #pragma unroll
    for (int s = 0; s < 4; ++s) {
      int dblk = 4 * s + lg;
      bf16x8 af = *reinterpret_cast<const bf16x8*>(
          &sNb[nrow * D_ + ((dblk ^ lr) & 15) * 8]);
      p0 = __builtin_amdgcn_mfma_f32_16x16x32_bf16(af, bC[0][s], p0, 0, 0, 0);
      p1 = __builtin_amdgcn_mfma_f32_16x16x32_bf16(af, bC[1][s], p1, 0, 0, 0);
    }
    float x2r[4];
    #pragma unroll
    for (int r = 0; r < 4; ++r) {
      float4 v = *reinterpret_cast<const float4*>(&sX2w[(m0 + lg * 4 + r) * 4]);
      x2r[r] = (v.x + v.y) + (v.z + v.w);
    }

    // ---- softmax over K=32 in-register ----
    float a0[4], a1[4], mr[4], sr[4];
    #pragma unroll
    for (int r = 0; r < 4; ++r) {
      float sl0 = sc0 * (x2r[r] - 2.f * p0[r] + c2p0);
      float sl1 = sc1 * (x2r[r] - 2.f * p1[r] + c2p1);
      a0[r] = sl0; a1[r] = sl1;
      mr[r] = fmaxf(sl0, sl1);
    }
    #pragma unroll
    for (int dlt = 1; dlt <= 8; dlt <<= 1)
      #pragma unroll
      for (int r = 0; r < 4; ++r) mr[r] = fmaxf(mr[r], __shfl_xor(mr[r], dlt));
    #pragma unroll
    for (int r = 0; r < 4; ++r) {
      a0[r] = __expf(a0[r] - mr[r]);
      a1[r] = __expf(a1[r] - mr[r]);
      sr[r] = a0[r] + a1[r];
    }
    #pragma unroll
    for (int dlt = 1; dlt <= 8; dlt <<= 1)
      #pragma unroll
      for (int r = 0; r < 4; ++r) sr[r] += __shfl_xor(sr[r], dlt);
    #pragma unroll
    for (int r = 0; r < 4; ++r) {
      float inv = 1.0f / sr[r];
      a0[r] *= inv; a1[r] *= inv;
    }

    // ---- block asum + A -> bf16 LDS tile ----
    float as0 = a0[0] + a0[1] + a0[2] + a0[3];
    float as1 = a1[0] + a1[1] + a1[2] + a1[3];
    as0 += __shfl_xor(as0, 16); as0 += __shfl_xor(as0, 32);
    as1 += __shfl_xor(as1, 16); as1 += __shfl_xor(as1, 32);
    if (lg == 0) {
      atomicAdd(&sasum[lr], as0);
      atomicAdd(&sasum[lr + 16], as1);
    }
    #pragma unroll
    for (int r = 0; r < 4; ++r) {
      int n = m0 + lg * 4 + r;
      sAb[lr * 64 + (n ^ ((lr & 7) << 3))] = f2b(a0[r]);
      sAb[(lr + 16) * 64 + (n ^ (((lr + 16) & 7) << 3))] = f2b(a1[r]);
    }
    __syncthreads();

    // ---- pass 2 accumulate: E += A^T X ----
    bf16x8 aA[2][2];
    #pragma unroll
    for (int mt = 0; mt < 2; ++mt) {
      int k = mt * 16 + lr;
      #pragma unroll
      for (int s = 0; s < 2; ++s) {
        int nb = 32 * s + lg * 8;
        aA[mt][s] = *reinterpret_cast<const bf16x8*>(
            &sAb[k * 64 + (nb ^ ((k & 7) << 3))]);
      }
    }
    #pragma unroll
    for (int mt = 0; mt < 2; ++mt)
      #pragma unroll
      for (int r = 0; r < 4; ++r) asvT[mt][r] += sasum[mt * 16 + lg * 4 + r];
    #pragma unroll
    for (int s = 0; s < 2; ++s) {
      #pragma unroll
      for (int dti = 0; dti < 2; ++dti) {
        int d = (2 * w + dti) * 16 + lr;
        int phys = (((4 * s + lg) ^ (d & 7) ^ ((d >> 3) & 7)) & 7);
        bf16x8 bf = *reinterpret_cast<const bf16x8*>(&sDb[d * NPB + phys * 8]);
        acc[0][dti] = __builtin_amdgcn_mfma_f32_16x16x32_bf16(aA[0][s], bf, acc[0][dti], 0, 0, 0);
        acc[1][dti] = __builtin_amdgcn_mfma_f32_16x16x32_bf16(aA[1][s], bf, acc[1][dti], 0, 0, 0);
      }
    }
    __syncthreads();                      // LDS free for next tile

    if (tile == 0) {
      if (t < K_) sasum[t] = 0.0f;
      STAGE_TILE();
      __syncthreads();
    }
  }

  // ---- epilogue: -asum*C correction + plain coalesced store to workspace ----
  float* wp = ws + (size_t)blockIdx.x * (K_ * D_);
  #pragma unroll
  for (int mt = 0; mt < 2; ++mt)
    #pragma unroll
    for (int dti = 0; dti < 2; ++dti) {
      int d = (2 * w + dti) * 16 + lr;
      #pragma unroll
      for (int r = 0; r < 4; ++r) {
        int k = mt * 16 + lg * 4 + r;
        wp[k * D_ + d] = acc[mt][dti][r] - asvT[mt][r] * cw[k * D_ + d];
      }
    }
}

// out[b][kd] = sum_{t<32} ws[b*32+t][kd]; 4 floats per thread, coalesced.
__global__ __launch_bounds__(256) void reduce_kernel(
    const float* __restrict__ ws, float* __restrict__ out)
{
  int g = blockIdx.x * 256 + threadIdx.x;       // 16384 threads
  int b = g >> 10;                              // 1024 float4 per b
  int q = g & 1023;
  const float4* base = reinterpret_cast<const float4*>(ws) + (size_t)b * 32 * 1024 + q;
  float4 s = {0.f, 0.f, 0.f, 0.f};
  #pragma unroll
  for (int t = 0; t < 32; ++t) {
    float4 v = base[(size_t)t * 1024];
    s.x += v.x; s.y += v.y; s.z += v.z; s.w += v.w;
  }
  reinterpret_cast<float4*>(out)[g] = s;
}

extern "C" void kernel_launch(void* const* d_in, const int* in_sizes, int n_in,
                              void* d_out, int out_size, void* d_ws, size_t ws_size,
                              hipStream_t stream) {
  const float* x  = (const float*)d_in[0];
  const float* cw = (const float*)d_in[1];
  const float* sc = (const float*)d_in[2];
  float* out = (float*)d_out;
  float* ws  = (float*)d_ws;
  const int B = in_sizes[0] / (D_ * NTOT);   // 16
  enc_kernel<<<dim3(B * 32), dim3(256), 0, stream>>>(x, cw, sc, ws);
  reduce_kernel<<<dim3(B * 4096 / 4 / 256), dim3(256), 0, stream>>>(ws, out);
}